// Round 1
// baseline (557.783 us; speedup 1.0000x reference)
//
#include <hip/hip_runtime.h>

// Problem constants (from reference): N=4096 agents, TOP_K=12, OBS_RADIUS=1.0
#define NN    4096
#define TOPK  12
#define NP    (NN * TOPK)        // 49152 pairs
// d_out layout (float32): out[0..NP), mask[NP..2NP), indices[2NP..2NP+2NP) as (row, j)
#define OFF_MASK (NP)
#define OFF_IDX  (2 * NP)

// ---------------------------------------------------------------------------
// K0: transpose W3 [64][128] -> W3t [128][64] so the MLP streams it contiguously
// ---------------------------------------------------------------------------
__global__ void transpose_w3(const float* __restrict__ W3, float* __restrict__ W3t) {
    int idx = blockIdx.x * 256 + threadIdx.x;     // 0..8191
    int m = idx >> 7;                             // 0..63  (output row of W3)
    int j = idx & 127;                            // 0..127 (input col)
    W3t[j * 64 + m] = W3[idx];
}

// ---------------------------------------------------------------------------
// K1: per-row top-12 smallest squared 2D distance. One block (256 thr) per row.
// Each thread holds its 16 candidate s-values in registers; 12 rounds of
// wave-butterfly + cross-wave min; only the owning thread rescans after a pop.
// Tie-break: smaller j wins (matches jax.lax.top_k).
// ---------------------------------------------------------------------------
__global__ __launch_bounds__(256) void topk_rows(const float* __restrict__ x,
                                                 float* __restrict__ out) {
    const int i = blockIdx.x;     // row
    const int t = threadIdx.x;    // 0..255
    const float4* x4 = (const float4*)x + (size_t)i * NN;

    // Stage: j = k*256 + t  (coalesced float4 loads)
    float s[16];
    #pragma unroll
    for (int k = 0; k < 16; ++k) {
        float4 v = x4[(k << 8) + t];
        s[k] = v.x * v.x + v.y * v.y;
    }

    // Local proposal: min over my 16 (ascending j order, strict < -> lowest j on tie)
    float bs = s[0];
    int   bj = t;
    #pragma unroll
    for (int k = 1; k < 16; ++k) {
        int j = (k << 8) + t;
        if (s[k] < bs) { bs = s[k]; bj = j; }
    }

    __shared__ float red_s[4];
    __shared__ int   red_j[4];
    __shared__ int   sel[TOPK];

    for (int it = 0; it < TOPK; ++it) {
        // 64-lane butterfly min on (s, j) lexicographic
        float vs = bs;
        int   vj = bj;
        #pragma unroll
        for (int off = 1; off < 64; off <<= 1) {
            float os = __shfl_xor(vs, off, 64);
            int   oj = __shfl_xor(vj, off, 64);
            if (os < vs || (os == vs && oj < vj)) { vs = os; vj = oj; }
        }
        int wid = t >> 6;
        if ((t & 63) == 0) { red_s[wid] = vs; red_j[wid] = vj; }
        __syncthreads();
        float ms = red_s[0];
        int   mj = red_j[0];
        #pragma unroll
        for (int w = 1; w < 4; ++w) {
            float osw = red_s[w]; int ojw = red_j[w];
            if (osw < ms || (osw == ms && ojw < mj)) { ms = osw; mj = ojw; }
        }
        if (t == 0) sel[it] = mj;
        // Owner (thread mj&255) pops mj and refreshes its proposal
        if ((mj & 255) == t) {
            int kk = mj >> 8;
            #pragma unroll
            for (int k = 0; k < 16; ++k)
                if (k == kk) s[k] = 3.0e38f;
            bs = s[0]; bj = t;
            #pragma unroll
            for (int k = 1; k < 16; ++k) {
                int j = (k << 8) + t;
                if (s[k] < bs) { bs = s[k]; bj = j; }
            }
        }
        __syncthreads();
    }

    // Epilogue: mask + indices outputs for the 12 selected
    if (t < TOPK) {
        int j = sel[t];
        float4 v = x4[j];
        float ss = v.x * v.x + v.y * v.y;
        float d  = sqrtf(ss + 2.0e-4f);          // sqrt(sum(x[:2]^2 + 1e-4))
        float mask = (d <= 1.0f) ? 1.0f : 0.0f;
        int p = i * TOPK + t;
        out[OFF_MASK + p]        = mask;
        out[OFF_IDX + 2 * p]     = (float)i;
        out[OFF_IDX + 2 * p + 1] = (float)j;
    }
}

// ---------------------------------------------------------------------------
// K2: per-neighbor MLP 6->64->128->64->1, one lane per (i,k) pair.
// Weights are read via wave-uniform addresses -> scalar loads; each MAC is a
// single v_fmac_f32 with an SGPR operand. Layers 2+3 fused in j-chunks of 8 so
// unrolled code stays small. h1[64], h3[64], h2c[8] live in registers.
// ---------------------------------------------------------------------------
__global__ __launch_bounds__(256, 1) void mlp_pairs(
        const float* __restrict__ x, const float* __restrict__ rp,
        const float* __restrict__ W1, const float* __restrict__ b1,
        const float* __restrict__ W2, const float* __restrict__ b2,
        const float* __restrict__ W3t, const float* __restrict__ b3,
        const float* __restrict__ W4, const float* __restrict__ b4,
        float* out) {
    int p = blockIdx.x * 256 + threadIdx.x;       // 0..NP-1
    int i = p / TOPK;
    int j = (int)out[OFF_IDX + 2 * p + 1];        // written by topk_rows

    const float4* x4 = (const float4*)x;
    float4 v = x4[(size_t)i * NN + j];
    float ss = v.x * v.x + v.y * v.y;
    float d  = sqrtf(ss + 2.0e-4f);
    float r  = rp[0];
    float mask = (d <= 1.0f) ? 1.0f : 0.0f;

    float xin0 = v.x, xin1 = v.y, xin2 = v.z, xin3 = v.w;
    float xin4 = (i == j) ? 1.0f : 0.0f;
    float xin5 = d - r;

    // Layer 1: 6 -> 64
    float h1[64];
    #pragma unroll
    for (int m = 0; m < 64; ++m) {
        const float* w = W1 + m * 6;
        float a = b1[m];
        a += w[0] * xin0; a += w[1] * xin1; a += w[2] * xin2;
        a += w[3] * xin3; a += w[4] * xin4; a += w[5] * xin5;
        h1[m] = fmaxf(a, 0.0f);
    }

    // Layers 2+3 fused: 64 -> 128 -> 64, streamed in chunks of 8 h2 neurons
    float h3[64];
    #pragma unroll
    for (int m = 0; m < 64; ++m) h3[m] = b3[m];

    for (int jj = 0; jj < 128; jj += 8) {         // real loop: weight addrs uniform
        float h2c[8];
        #pragma unroll
        for (int q = 0; q < 8; ++q) {
            const float* w = W2 + (jj + q) * 64;  // W2 row-major [128][64]
            float a = b2[jj + q];
            #pragma unroll
            for (int k = 0; k < 64; ++k) a += w[k] * h1[k];
            h2c[q] = fmaxf(a, 0.0f);
        }
        #pragma unroll
        for (int q = 0; q < 8; ++q) {
            const float* w = W3t + (jj + q) * 64; // W3t [128][64]
            float hq = h2c[q];
            #pragma unroll
            for (int m = 0; m < 64; ++m) h3[m] += w[m] * hq;
        }
    }

    // Layer 4: 64 -> 1 (relu applied to h3 here)
    float o = b4[0];
    #pragma unroll
    for (int m = 0; m < 64; ++m) o += W4[m] * fmaxf(h3[m], 0.0f);

    out[p] = o * mask;
}

// ---------------------------------------------------------------------------
extern "C" void kernel_launch(void* const* d_in, const int* in_sizes, int n_in,
                              void* d_out, int out_size, void* d_ws, size_t ws_size,
                              hipStream_t stream) {
    const float* x  = (const float*)d_in[0];
    const float* rp = (const float*)d_in[1];
    const float* W1 = (const float*)d_in[2];
    const float* b1 = (const float*)d_in[3];
    const float* W2 = (const float*)d_in[4];
    const float* b2 = (const float*)d_in[5];
    const float* W3 = (const float*)d_in[6];
    const float* b3 = (const float*)d_in[7];
    const float* W4 = (const float*)d_in[8];
    const float* b4 = (const float*)d_in[9];
    float* out = (float*)d_out;
    float* W3t = (float*)d_ws;                    // 8192 floats = 32 KB

    transpose_w3<<<32, 256, 0, stream>>>(W3, W3t);
    topk_rows<<<NN, 256, 0, stream>>>(x, out);
    mlp_pairs<<<NP / 256, 256, 0, stream>>>(x, rp, W1, b1, W2, b2, W3t, b3, W4, b4, out);
}

// Round 2
// 503.921 us; speedup vs baseline: 1.1069x; 1.1069x over previous
//
#include <hip/hip_runtime.h>

// Problem constants (from reference): N=4096 agents, TOP_K=12, OBS_RADIUS=1.0
#define NN    4096
#define TOPK  12
#define NP    (NN * TOPK)        // 49152 pairs
// d_out layout (float32): out[0..NP), mask[NP..2NP), indices[2NP..2NP+2NP) as (row, j)
#define OFF_MASK (NP)
#define OFF_IDX  (2 * NP)

// ---------------------------------------------------------------------------
// K1: per-row top-12 smallest squared 2D distance. One block (256 thr) per row.
// (unchanged from round 1 — correct; will profile it in isolation next round)
// ---------------------------------------------------------------------------
__global__ __launch_bounds__(256) void topk_rows(const float* __restrict__ x,
                                                 float* __restrict__ out) {
    const int i = blockIdx.x;     // row
    const int t = threadIdx.x;    // 0..255
    const float4* x4 = (const float4*)x + (size_t)i * NN;

    float s[16];
    #pragma unroll
    for (int k = 0; k < 16; ++k) {
        float4 v = x4[(k << 8) + t];
        s[k] = v.x * v.x + v.y * v.y;
    }

    float bs = s[0];
    int   bj = t;
    #pragma unroll
    for (int k = 1; k < 16; ++k) {
        int j = (k << 8) + t;
        if (s[k] < bs) { bs = s[k]; bj = j; }
    }

    __shared__ float red_s[4];
    __shared__ int   red_j[4];
    __shared__ int   sel[TOPK];

    for (int it = 0; it < TOPK; ++it) {
        float vs = bs;
        int   vj = bj;
        #pragma unroll
        for (int off = 1; off < 64; off <<= 1) {
            float os = __shfl_xor(vs, off, 64);
            int   oj = __shfl_xor(vj, off, 64);
            if (os < vs || (os == vs && oj < vj)) { vs = os; vj = oj; }
        }
        int wid = t >> 6;
        if ((t & 63) == 0) { red_s[wid] = vs; red_j[wid] = vj; }
        __syncthreads();
        float ms = red_s[0];
        int   mj = red_j[0];
        #pragma unroll
        for (int w = 1; w < 4; ++w) {
            float osw = red_s[w]; int ojw = red_j[w];
            if (osw < ms || (osw == ms && ojw < mj)) { ms = osw; mj = ojw; }
        }
        if (t == 0) sel[it] = mj;
        if ((mj & 255) == t) {
            int kk = mj >> 8;
            #pragma unroll
            for (int k = 0; k < 16; ++k)
                if (k == kk) s[k] = 3.0e38f;
            bs = s[0]; bj = t;
            #pragma unroll
            for (int k = 1; k < 16; ++k) {
                int j = (k << 8) + t;
                if (s[k] < bs) { bs = s[k]; bj = j; }
            }
        }
        __syncthreads();
    }

    if (t < TOPK) {
        int j = sel[t];
        float4 v = x4[j];
        float ss = v.x * v.x + v.y * v.y;
        float d  = sqrtf(ss + 2.0e-4f);
        float mask = (d <= 1.0f) ? 1.0f : 0.0f;
        int p = i * TOPK + t;
        out[OFF_MASK + p]        = mask;
        out[OFF_IDX + 2 * p]     = (float)i;
        out[OFF_IDX + 2 * p + 1] = (float)j;
    }
}

// ---------------------------------------------------------------------------
// K2: per-neighbor MLP 6->64->128->64->1.
// Block = 512 threads = 8 waves handling 64 pairs: lane (t&63) = pair,
// wave (t>>6) = neuron chunk -> weight addresses stay wave-uniform (s_load),
// activations pass between layers via LDS in [neuron][pair] layout
// (lane = pair -> consecutive banks, conflict-free). 50 KB LDS -> 3 blocks/CU,
// 8x the wave count of the lane-per-pair version (768 -> 6144 waves).
// ---------------------------------------------------------------------------
__global__ __launch_bounds__(512, 6) void mlp_block(
        const float* __restrict__ x, const float* __restrict__ rp,
        const float* __restrict__ W1, const float* __restrict__ b1,
        const float* __restrict__ W2, const float* __restrict__ b2,
        const float* __restrict__ W3, const float* __restrict__ b3,
        const float* __restrict__ W4, const float* __restrict__ b4,
        float* out) {
    __shared__ float h1s[64 * 64];    // [m][pair] 16 KB
    __shared__ float h2s[128 * 64];   // [j][pair] 32 KB
    __shared__ float p4s[8 * 64];     // [chunk][pair] 2 KB

    const int t  = threadIdx.x;
    const int pl = t & 63;            // pair lane 0..63
    const int ch = t >> 6;            // wave chunk 0..7 (wave-uniform)
    const int p  = blockIdx.x * 64 + pl;
    const int i  = p / TOPK;
    const int j  = (int)out[OFF_IDX + 2 * p + 1];   // written by topk_rows

    const float4 v = ((const float4*)x)[(size_t)i * NN + j];
    const float d  = sqrtf(v.x * v.x + v.y * v.y + 2.0e-4f);
    float xin[6];
    xin[0] = v.x; xin[1] = v.y; xin[2] = v.z; xin[3] = v.w;
    xin[4] = (i == j) ? 1.0f : 0.0f;
    xin[5] = d - rp[0];

    // Phase 1: h1 neurons [ch*8, ch*8+8)
    #pragma unroll
    for (int q = 0; q < 8; ++q) {
        int m = ch * 8 + q;
        const float* w = W1 + m * 6;
        float a = b1[m];
        #pragma unroll
        for (int c = 0; c < 6; ++c) a += w[c] * xin[c];
        h1s[m * 64 + pl] = fmaxf(a, 0.0f);
    }
    __syncthreads();

    // Phase 2: h2 neurons [ch*16, ch*16+16), k streamed in parts of 16
    float acc[16];
    #pragma unroll
    for (int q = 0; q < 16; ++q) acc[q] = b2[ch * 16 + q];
    for (int part = 0; part < 4; ++part) {
        float h1r[16];
        #pragma unroll
        for (int k = 0; k < 16; ++k) h1r[k] = h1s[(part * 16 + k) * 64 + pl];
        #pragma unroll
        for (int q = 0; q < 16; ++q) {
            const float* w = W2 + (ch * 16 + q) * 64 + part * 16;
            #pragma unroll
            for (int k = 0; k < 16; ++k) acc[q] += w[k] * h1r[k];
        }
    }
    #pragma unroll
    for (int q = 0; q < 16; ++q) h2s[(ch * 16 + q) * 64 + pl] = fmaxf(acc[q], 0.0f);
    __syncthreads();

    // Phase 3: h3 neurons [ch*8, ch*8+8), j streamed in parts of 16
    float h3[8];
    #pragma unroll
    for (int q = 0; q < 8; ++q) h3[q] = b3[ch * 8 + q];
    for (int part = 0; part < 8; ++part) {
        float h2r[16];
        #pragma unroll
        for (int k = 0; k < 16; ++k) h2r[k] = h2s[(part * 16 + k) * 64 + pl];
        #pragma unroll
        for (int q = 0; q < 8; ++q) {
            const float* w = W3 + (ch * 8 + q) * 128 + part * 16;
            #pragma unroll
            for (int k = 0; k < 16; ++k) h3[q] += w[k] * h2r[k];
        }
    }
    // Layer 4 partial over my 8 h3 outputs
    float partial = 0.0f;
    #pragma unroll
    for (int q = 0; q < 8; ++q) partial += W4[ch * 8 + q] * fmaxf(h3[q], 0.0f);
    p4s[ch * 64 + pl] = partial;
    __syncthreads();

    // Phase 4: reduce the 8 chunk-partials per pair, apply bias + mask
    if (t < 64) {
        float s = b4[0];
        #pragma unroll
        for (int c = 0; c < 8; ++c) s += p4s[c * 64 + t];
        int pp = blockIdx.x * 64 + t;
        out[pp] = s * out[OFF_MASK + pp];
    }
}

// ---------------------------------------------------------------------------
extern "C" void kernel_launch(void* const* d_in, const int* in_sizes, int n_in,
                              void* d_out, int out_size, void* d_ws, size_t ws_size,
                              hipStream_t stream) {
    const float* x  = (const float*)d_in[0];
    const float* rp = (const float*)d_in[1];
    const float* W1 = (const float*)d_in[2];
    const float* b1 = (const float*)d_in[3];
    const float* W2 = (const float*)d_in[4];
    const float* b2 = (const float*)d_in[5];
    const float* W3 = (const float*)d_in[6];
    const float* b3 = (const float*)d_in[7];
    const float* W4 = (const float*)d_in[8];
    const float* b4 = (const float*)d_in[9];
    float* out = (float*)d_out;

    topk_rows<<<NN, 256, 0, stream>>>(x, out);
    mlp_block<<<NP / 64, 512, 0, stream>>>(x, rp, W1, b1, W2, b2, W3, b3, W4, b4, out);
}

// Round 3
// 418.182 us; speedup vs baseline: 1.3338x; 1.2050x over previous
//
#include <hip/hip_runtime.h>

// Problem constants (from reference): N=4096 agents, TOP_K=12, OBS_RADIUS=1.0
#define NN    4096
#define TOPK  12
#define NP    (NN * TOPK)        // 49152 pairs
// d_out layout (float32): out[0..NP), mask[NP..2NP), indices[2NP..2NP+2NP) as (row, j)
#define OFF_MASK (NP)
#define OFF_IDX  (2 * NP)

// ---------------------------------------------------------------------------
// K1: per-row top-12 smallest squared 2D distance. One block (256 thr) per row.
// (unchanged — inferred ~95 us vs 40 us HBM floor; profile next round)
// ---------------------------------------------------------------------------
__global__ __launch_bounds__(256) void topk_rows(const float* __restrict__ x,
                                                 float* __restrict__ out) {
    const int i = blockIdx.x;     // row
    const int t = threadIdx.x;    // 0..255
    const float4* x4 = (const float4*)x + (size_t)i * NN;

    float s[16];
    #pragma unroll
    for (int k = 0; k < 16; ++k) {
        float4 v = x4[(k << 8) + t];
        s[k] = v.x * v.x + v.y * v.y;
    }

    float bs = s[0];
    int   bj = t;
    #pragma unroll
    for (int k = 1; k < 16; ++k) {
        int j = (k << 8) + t;
        if (s[k] < bs) { bs = s[k]; bj = j; }
    }

    __shared__ float red_s[4];
    __shared__ int   red_j[4];
    __shared__ int   sel[TOPK];

    for (int it = 0; it < TOPK; ++it) {
        float vs = bs;
        int   vj = bj;
        #pragma unroll
        for (int off = 1; off < 64; off <<= 1) {
            float os = __shfl_xor(vs, off, 64);
            int   oj = __shfl_xor(vj, off, 64);
            if (os < vs || (os == vs && oj < vj)) { vs = os; vj = oj; }
        }
        int wid = t >> 6;
        if ((t & 63) == 0) { red_s[wid] = vs; red_j[wid] = vj; }
        __syncthreads();
        float ms = red_s[0];
        int   mj = red_j[0];
        #pragma unroll
        for (int w = 1; w < 4; ++w) {
            float osw = red_s[w]; int ojw = red_j[w];
            if (osw < ms || (osw == ms && ojw < mj)) { ms = osw; mj = ojw; }
        }
        if (t == 0) sel[it] = mj;
        if ((mj & 255) == t) {
            int kk = mj >> 8;
            #pragma unroll
            for (int k = 0; k < 16; ++k)
                if (k == kk) s[k] = 3.0e38f;
            bs = s[0]; bj = t;
            #pragma unroll
            for (int k = 1; k < 16; ++k) {
                int j = (k << 8) + t;
                if (s[k] < bs) { bs = s[k]; bj = j; }
            }
        }
        __syncthreads();
    }

    if (t < TOPK) {
        int j = sel[t];
        float4 v = x4[j];
        float ss = v.x * v.x + v.y * v.y;
        float d  = sqrtf(ss + 2.0e-4f);
        float mask = (d <= 1.0f) ? 1.0f : 0.0f;
        int p = i * TOPK + t;
        out[OFF_MASK + p]        = mask;
        out[OFF_IDX + 2 * p]     = (float)i;
        out[OFF_IDX + 2 * p + 1] = (float)j;
    }
}

// ---------------------------------------------------------------------------
// K2: per-neighbor MLP 6->64->128->64->1.
// Block = 512 threads = 8 waves handling 64 pairs: lane (t&63) = pair,
// wave chunk ch = readfirstlane(t>>6) -> SGPR, so ALL weight/bias addresses
// are compiler-provably scalar => s_load_dwordx16 + v_fmac_f32(v,s,v), zero
// VMEM in the inner loops (round-2 version compiled them to broadcast
// global_load_dword because t>>6 isn't provably uniform -> 5x slowdown).
// Activations pass via LDS [neuron][pair] (lane=pair -> conflict-free).
// 50 KB LDS -> 3 blocks/CU, 24 waves/CU.
// ---------------------------------------------------------------------------
__global__ __launch_bounds__(512, 6) void mlp_block(
        const float* __restrict__ x, const float* __restrict__ rp,
        const float* __restrict__ W1, const float* __restrict__ b1,
        const float* __restrict__ W2, const float* __restrict__ b2,
        const float* __restrict__ W3, const float* __restrict__ b3,
        const float* __restrict__ W4, const float* __restrict__ b4,
        float* out) {
    __shared__ float h1s[64 * 64];    // [m][pair] 16 KB
    __shared__ float h2s[128 * 64];   // [j][pair] 32 KB
    __shared__ float p4s[8 * 64];     // [chunk][pair] 2 KB

    const int t  = threadIdx.x;
    const int pl = t & 63;                                   // pair lane (vector)
    const int ch = __builtin_amdgcn_readfirstlane(t >> 6);   // chunk (SGPR!)
    const int p  = blockIdx.x * 64 + pl;
    const int i  = p / TOPK;
    const int j  = (int)out[OFF_IDX + 2 * p + 1];   // written by topk_rows

    const float4 v = ((const float4*)x)[(size_t)i * NN + j];
    const float d  = sqrtf(v.x * v.x + v.y * v.y + 2.0e-4f);
    float xin[6];
    xin[0] = v.x; xin[1] = v.y; xin[2] = v.z; xin[3] = v.w;
    xin[4] = (i == j) ? 1.0f : 0.0f;
    xin[5] = d - rp[0];

    // Phase 1: h1 neurons [ch*8, ch*8+8)   (weights via s_load)
    #pragma unroll
    for (int q = 0; q < 8; ++q) {
        int m = ch * 8 + q;
        const float* w = W1 + m * 6;
        float a = b1[m];
        #pragma unroll
        for (int c = 0; c < 6; ++c) a += w[c] * xin[c];
        h1s[m * 64 + pl] = fmaxf(a, 0.0f);
    }
    __syncthreads();

    // Phase 2: h2 neurons [ch*16, ch*16+16), k streamed in parts of 16
    float acc[16];
    #pragma unroll
    for (int q = 0; q < 16; ++q) acc[q] = b2[ch * 16 + q];
    for (int part = 0; part < 4; ++part) {
        float h1r[16];
        #pragma unroll
        for (int k = 0; k < 16; ++k) h1r[k] = h1s[(part * 16 + k) * 64 + pl];
        #pragma unroll
        for (int q = 0; q < 16; ++q) {
            const float* w = W2 + (ch * 16 + q) * 64 + part * 16;  // scalar addr
            #pragma unroll
            for (int k = 0; k < 16; ++k) acc[q] += w[k] * h1r[k];
        }
    }
    #pragma unroll
    for (int q = 0; q < 16; ++q) h2s[(ch * 16 + q) * 64 + pl] = fmaxf(acc[q], 0.0f);
    __syncthreads();

    // Phase 3: h3 neurons [ch*8, ch*8+8), j streamed in parts of 16
    float h3[8];
    #pragma unroll
    for (int q = 0; q < 8; ++q) h3[q] = b3[ch * 8 + q];
    for (int part = 0; part < 8; ++part) {
        float h2r[16];
        #pragma unroll
        for (int k = 0; k < 16; ++k) h2r[k] = h2s[(part * 16 + k) * 64 + pl];
        #pragma unroll
        for (int q = 0; q < 8; ++q) {
            const float* w = W3 + (ch * 8 + q) * 128 + part * 16;  // scalar addr
            #pragma unroll
            for (int k = 0; k < 16; ++k) h3[q] += w[k] * h2r[k];
        }
    }
    // Layer 4 partial over my 8 h3 outputs
    float partial = 0.0f;
    #pragma unroll
    for (int q = 0; q < 8; ++q) partial += W4[ch * 8 + q] * fmaxf(h3[q], 0.0f);
    p4s[ch * 64 + pl] = partial;
    __syncthreads();

    // Phase 4: reduce the 8 chunk-partials per pair, apply bias + mask
    if (t < 64) {
        float s = b4[0];
        #pragma unroll
        for (int c = 0; c < 8; ++c) s += p4s[c * 64 + t];
        int pp = blockIdx.x * 64 + t;
        out[pp] = s * out[OFF_MASK + pp];
    }
}

// ---------------------------------------------------------------------------
extern "C" void kernel_launch(void* const* d_in, const int* in_sizes, int n_in,
                              void* d_out, int out_size, void* d_ws, size_t ws_size,
                              hipStream_t stream) {
    const float* x  = (const float*)d_in[0];
    const float* rp = (const float*)d_in[1];
    const float* W1 = (const float*)d_in[2];
    const float* b1 = (const float*)d_in[3];
    const float* W2 = (const float*)d_in[4];
    const float* b2 = (const float*)d_in[5];
    const float* W3 = (const float*)d_in[6];
    const float* b3 = (const float*)d_in[7];
    const float* W4 = (const float*)d_in[8];
    const float* b4 = (const float*)d_in[9];
    float* out = (float*)d_out;

    topk_rows<<<NN, 256, 0, stream>>>(x, out);
    mlp_block<<<NP / 64, 512, 0, stream>>>(x, rp, W1, b1, W2, b2, W3, b3, W4, b4, out);
}

// Round 4
// 412.452 us; speedup vs baseline: 1.3524x; 1.0139x over previous
//
#include <hip/hip_runtime.h>

// Problem constants (from reference): N=4096 agents, TOP_K=12, OBS_RADIUS=1.0
#define NN    4096
#define TOPK  12
#define NP    (NN * TOPK)        // 49152 pairs
// d_out layout (float32): out[0..NP), mask[NP..2NP), indices[2NP..2NP+2NP) as (row, j)
#define OFF_MASK (NP)
#define OFF_IDX  (2 * NP)

// ---------------------------------------------------------------------------
// K1: per-row top-12 smallest squared 2D distance. One block (256 thr) per row.
// Round-4 restructure: wave-local pops (no barriers) + single merge.
//  - key = (f32 bits of s)<<32 | j : s>=0 so u64 order == (s, j) lexicographic,
//    identical ordering/tie-break to the previous passing kernel.
//  - each wave pops its own top-12 of its 1024 candidates via 64-lane
//    butterfly min on u64 keys (implicit wave sync, NO __syncthreads).
//  - ONE __syncthreads; wave 0 bitonic-sorts the 48 candidates (padded to 64
//    with +inf keys) in 21 stages and writes mask/indices from the key bits.
// Previous version had 24 block-wide barriers around dependent shuffle chains
// (a convoy that also starved the HBM pipe between block generations).
// ---------------------------------------------------------------------------
__global__ __launch_bounds__(256, 6) void topk_rows(const float* __restrict__ x,
                                                    float* __restrict__ out) {
    const int i    = blockIdx.x;   // row
    const int t    = threadIdx.x;  // 0..255
    const int lane = t & 63;
    const int w    = t >> 6;       // wave 0..3
    const float4* x4 = (const float4*)x + (size_t)i * NN;

    // Stage: j = k*256 + t  (coalesced float4 loads)
    float s[16];
    #pragma unroll
    for (int k = 0; k < 16; ++k) {
        float4 v = x4[(k << 8) + t];
        s[k] = v.x * v.x + v.y * v.y;
    }

    // Local best as packed key (ascending j scan, strict < => lowest j on tie)
    unsigned long long bk;
    {
        float bs = s[0]; int bj = t;
        #pragma unroll
        for (int k = 1; k < 16; ++k) {
            int j = (k << 8) + t;
            if (s[k] < bs) { bs = s[k]; bj = j; }
        }
        bk = ((unsigned long long)__float_as_uint(bs) << 32) | (unsigned)bj;
    }

    __shared__ unsigned long long cand[4 * TOPK];   // 384 B

    unsigned long long mykey = ~0ULL;

    // 12 wave-local pops, barrier-free
    for (int it = 0; it < TOPK; ++it) {
        unsigned long long vk = bk;
        #pragma unroll
        for (int off = 1; off < 64; off <<= 1) {
            unsigned long long ok = __shfl_xor(vk, off, 64);
            vk = (ok < vk) ? ok : vk;
        }
        if (lane == it) mykey = vk;                 // record pop #it
        int wj = (int)(vk & 0xffffffffULL);         // winning j (this wave's range)
        if ((wj & 63) == lane) {                    // I own it: pop + recompute
            int kk = wj >> 8;
            #pragma unroll
            for (int k = 0; k < 16; ++k)
                if (k == kk) s[k] = 3.0e38f;
            float bs = s[0]; int bj = t;
            #pragma unroll
            for (int k = 1; k < 16; ++k) {
                int j = (k << 8) + t;
                if (s[k] < bs) { bs = s[k]; bj = j; }
            }
            bk = ((unsigned long long)__float_as_uint(bs) << 32) | (unsigned)bj;
        }
    }

    if (lane < TOPK) cand[w * TOPK + lane] = mykey;
    __syncthreads();                                 // the only barrier

    if (w == 0) {
        // 64-lane bitonic sort, ascending by u64 key; lanes 48..63 = +inf pad
        unsigned long long key = (lane < 4 * TOPK) ? cand[lane] : ~0ULL;
        #pragma unroll
        for (int k = 2; k <= 64; k <<= 1) {
            #pragma unroll
            for (int jj = k >> 1; jj >= 1; jj >>= 1) {
                unsigned long long ok = __shfl_xor(key, jj, 64);
                bool keepMin = ((lane & k) == 0) == ((lane & jj) == 0);
                unsigned long long mn = (ok < key) ? ok : key;
                unsigned long long mx = (ok < key) ? key : ok;
                key = keepMin ? mn : mx;
            }
        }
        if (lane < TOPK) {
            int   j  = (int)(key & 0xffffffffULL);
            float ss = __uint_as_float((unsigned)(key >> 32));
            float d  = sqrtf(ss + 2.0e-4f);          // sqrt(sum(x[:2]^2 + 1e-4))
            float mask = (d <= 1.0f) ? 1.0f : 0.0f;
            int p = i * TOPK + lane;
            out[OFF_MASK + p]        = mask;
            out[OFF_IDX + 2 * p]     = (float)i;
            out[OFF_IDX + 2 * p + 1] = (float)j;
        }
    }
}

// ---------------------------------------------------------------------------
// K2: per-neighbor MLP 6->64->128->64->1.  (unchanged this round)
// Block = 512 threads = 8 waves handling 64 pairs: lane (t&63) = pair,
// wave chunk ch = readfirstlane(t>>6) -> SGPR, so ALL weight/bias addresses
// are compiler-provably scalar => s_load + v_fmac_f32(v,s,v), zero VMEM in
// the inner loops. Activations pass via LDS [neuron][pair] (lane=pair ->
// conflict-free). 50 KB LDS -> 3 blocks/CU, 24 waves/CU.
// ---------------------------------------------------------------------------
__global__ __launch_bounds__(512, 6) void mlp_block(
        const float* __restrict__ x, const float* __restrict__ rp,
        const float* __restrict__ W1, const float* __restrict__ b1,
        const float* __restrict__ W2, const float* __restrict__ b2,
        const float* __restrict__ W3, const float* __restrict__ b3,
        const float* __restrict__ W4, const float* __restrict__ b4,
        float* out) {
    __shared__ float h1s[64 * 64];    // [m][pair] 16 KB
    __shared__ float h2s[128 * 64];   // [j][pair] 32 KB
    __shared__ float p4s[8 * 64];     // [chunk][pair] 2 KB

    const int t  = threadIdx.x;
    const int pl = t & 63;                                   // pair lane (vector)
    const int ch = __builtin_amdgcn_readfirstlane(t >> 6);   // chunk (SGPR!)
    const int p  = blockIdx.x * 64 + pl;
    const int i  = p / TOPK;
    const int j  = (int)out[OFF_IDX + 2 * p + 1];   // written by topk_rows

    const float4 v = ((const float4*)x)[(size_t)i * NN + j];
    const float d  = sqrtf(v.x * v.x + v.y * v.y + 2.0e-4f);
    float xin[6];
    xin[0] = v.x; xin[1] = v.y; xin[2] = v.z; xin[3] = v.w;
    xin[4] = (i == j) ? 1.0f : 0.0f;
    xin[5] = d - rp[0];

    // Phase 1: h1 neurons [ch*8, ch*8+8)   (weights via s_load)
    #pragma unroll
    for (int q = 0; q < 8; ++q) {
        int m = ch * 8 + q;
        const float* w = W1 + m * 6;
        float a = b1[m];
        #pragma unroll
        for (int c = 0; c < 6; ++c) a += w[c] * xin[c];
        h1s[m * 64 + pl] = fmaxf(a, 0.0f);
    }
    __syncthreads();

    // Phase 2: h2 neurons [ch*16, ch*16+16), k streamed in parts of 16
    float acc[16];
    #pragma unroll
    for (int q = 0; q < 16; ++q) acc[q] = b2[ch * 16 + q];
    for (int part = 0; part < 4; ++part) {
        float h1r[16];
        #pragma unroll
        for (int k = 0; k < 16; ++k) h1r[k] = h1s[(part * 16 + k) * 64 + pl];
        #pragma unroll
        for (int q = 0; q < 16; ++q) {
            const float* w = W2 + (ch * 16 + q) * 64 + part * 16;  // scalar addr
            #pragma unroll
            for (int k = 0; k < 16; ++k) acc[q] += w[k] * h1r[k];
        }
    }
    #pragma unroll
    for (int q = 0; q < 16; ++q) h2s[(ch * 16 + q) * 64 + pl] = fmaxf(acc[q], 0.0f);
    __syncthreads();

    // Phase 3: h3 neurons [ch*8, ch*8+8), j streamed in parts of 16
    float h3[8];
    #pragma unroll
    for (int q = 0; q < 8; ++q) h3[q] = b3[ch * 8 + q];
    for (int part = 0; part < 8; ++part) {
        float h2r[16];
        #pragma unroll
        for (int k = 0; k < 16; ++k) h2r[k] = h2s[(part * 16 + k) * 64 + pl];
        #pragma unroll
        for (int q = 0; q < 8; ++q) {
            const float* w = W3 + (ch * 8 + q) * 128 + part * 16;  // scalar addr
            #pragma unroll
            for (int k = 0; k < 16; ++k) h3[q] += w[k] * h2r[k];
        }
    }
    // Layer 4 partial over my 8 h3 outputs
    float partial = 0.0f;
    #pragma unroll
    for (int q = 0; q < 8; ++q) partial += W4[ch * 8 + q] * fmaxf(h3[q], 0.0f);
    p4s[ch * 64 + pl] = partial;
    __syncthreads();

    // Phase 4: reduce the 8 chunk-partials per pair, apply bias + mask
    if (t < 64) {
        float s = b4[0];
        #pragma unroll
        for (int c = 0; c < 8; ++c) s += p4s[c * 64 + t];
        int pp = blockIdx.x * 64 + t;
        out[pp] = s * out[OFF_MASK + pp];
    }
}

// ---------------------------------------------------------------------------
extern "C" void kernel_launch(void* const* d_in, const int* in_sizes, int n_in,
                              void* d_out, int out_size, void* d_ws, size_t ws_size,
                              hipStream_t stream) {
    const float* x  = (const float*)d_in[0];
    const float* rp = (const float*)d_in[1];
    const float* W1 = (const float*)d_in[2];
    const float* b1 = (const float*)d_in[3];
    const float* W2 = (const float*)d_in[4];
    const float* b2 = (const float*)d_in[5];
    const float* W3 = (const float*)d_in[6];
    const float* b3 = (const float*)d_in[7];
    const float* W4 = (const float*)d_in[8];
    const float* b4 = (const float*)d_in[9];
    float* out = (float*)d_out;

    topk_rows<<<NN, 256, 0, stream>>>(x, out);
    mlp_block<<<NP / 64, 512, 0, stream>>>(x, rp, W1, b1, W2, b2, W3, b3, W4, b4, out);
}